// Round 4
// baseline (327.172 us; speedup 1.0000x reference)
//
#include <hip/hip_runtime.h>

// Problem constants (reference setup_inputs: mask [64, 512, 896] f32)
#define B 64
#define H 512
#define W 896
#define W4 (W / 4)                  // 224 float4 per row
#define PIX (H * W)                 // 458752 per batch
#define VEC (PIX / 4)               // 114688 float4 per batch
#define TPB 256
#define SLICES 32                   // blocks per batch
#define VEC_SLICE (VEC / SLICES)    // 3584 float4 per block
#define ITERS (VEC_SLICE / TPB)     // 14 float4 per thread
#define NBLK (B * SLICES)           // 2048 blocks
#define PT 0.5f
#define MAGIC 0x5A5A5A5A

// ws int layout:
//   [0 .. B)                      per-batch arrival counters  (memset to 0 each call)
//   [64 .. 64+5*NBLK)             partials: cnt,rmn,rmx,cmn,cmx  (written exactly once)
//   [64+5*NBLK .. +B*8)           per-batch box: {flag, rmn, rmx, cmn, cmx, pad[3]}
#define P_OFF 64
#define X_OFF (P_OFF + 5 * NBLK)

__global__ __launch_bounds__(TPB) void rag_fused_kernel(
        const float* __restrict__ mask,
        const int* __restrict__ nthr_p,
        const int* __restrict__ dthr_p,
        float* __restrict__ out,
        int* __restrict__ ws) {
    const int bid = blockIdx.x;          // 0..NBLK-1
    const int b   = bid >> 5;            // batch (SLICES == 32)
    const int tid = threadIdx.x;
    const int sbase = (bid & (SLICES - 1)) * VEC_SLICE + tid;

    // ---------------- Phase 1: per-slice count + bbox reduction ----------------
    const float4* m = reinterpret_cast<const float4*>(mask) + (size_t)b * VEC;

    int cnt = 0, rmn = H, rmx = -1, cmn = W, cmx = -1;

#pragma unroll
    for (int it = 0; it < ITERS; ++it) {
        const int i4 = sbase + it * TPB;
        const float4 v = m[i4];
        const bool f0 = v.x > PT;
        const bool f1 = v.y > PT;
        const bool f2 = v.z > PT;
        const bool f3 = v.w > PT;
        cnt += (int)f0 + (int)f1 + (int)f2 + (int)f3;
        if (f0 | f1 | f2 | f3) {
            const int row = i4 / W4;
            const int col = (i4 - row * W4) * 4;
            rmn = min(rmn, row);
            rmx = max(rmx, row);
            const int clo = f0 ? col : (f1 ? col + 1 : (f2 ? col + 2 : col + 3));
            const int chi = f3 ? col + 3 : (f2 ? col + 2 : (f1 ? col + 1 : col));
            cmn = min(cmn, clo);
            cmx = max(cmx, chi);
        }
    }

    // Wave-64 reduce.
#pragma unroll
    for (int off = 32; off > 0; off >>= 1) {
        cnt += __shfl_down(cnt, off);
        rmn = min(rmn, __shfl_down(rmn, off));
        rmx = max(rmx, __shfl_down(rmx, off));
        cmn = min(cmn, __shfl_down(cmn, off));
        cmx = max(cmx, __shfl_down(cmx, off));
    }

    __shared__ int s[5][TPB / 64];
    __shared__ int s_last;
    __shared__ int sbox[4];
    const int wave = tid >> 6;
    if ((tid & 63) == 0) {
        s[0][wave] = cnt; s[1][wave] = rmn; s[2][wave] = rmx;
        s[3][wave] = cmn; s[4][wave] = cmx;
    }
    __syncthreads();
    if (tid == 0) {
#pragma unroll
        for (int wv = 1; wv < TPB / 64; ++wv) {
            cnt += s[0][wv];
            rmn = min(rmn, s[1][wv]);
            rmx = max(rmx, s[2][wv]);
            cmn = min(cmn, s[3][wv]);
            cmx = max(cmx, s[4][wv]);
        }
        // Publish this block's partial (one slot, written exactly once).
        __hip_atomic_store(&ws[P_OFF + 0 * NBLK + bid], cnt, __ATOMIC_RELAXED, __HIP_MEMORY_SCOPE_AGENT);
        __hip_atomic_store(&ws[P_OFF + 1 * NBLK + bid], rmn, __ATOMIC_RELAXED, __HIP_MEMORY_SCOPE_AGENT);
        __hip_atomic_store(&ws[P_OFF + 2 * NBLK + bid], rmx, __ATOMIC_RELAXED, __HIP_MEMORY_SCOPE_AGENT);
        __hip_atomic_store(&ws[P_OFF + 3 * NBLK + bid], cmn, __ATOMIC_RELAXED, __HIP_MEMORY_SCOPE_AGENT);
        __hip_atomic_store(&ws[P_OFF + 4 * NBLK + bid], cmx, __ATOMIC_RELAXED, __HIP_MEMORY_SCOPE_AGENT);
        // Arrival (release orders the partial stores above).
        const int old = __hip_atomic_fetch_add(&ws[b], 1, __ATOMIC_ACQ_REL, __HIP_MEMORY_SCOPE_AGENT);
        s_last = (old == SLICES - 1);
    }
    __syncthreads();

    // ---------------- Phase 2: last arriver finalizes the batch box ------------
    if (s_last && tid < 32) {
        const int q = (b << 5) + tid;    // 32 partial slots for this batch
        int c  = __hip_atomic_load(&ws[P_OFF + 0 * NBLK + q], __ATOMIC_RELAXED, __HIP_MEMORY_SCOPE_AGENT);
        int r0 = __hip_atomic_load(&ws[P_OFF + 1 * NBLK + q], __ATOMIC_RELAXED, __HIP_MEMORY_SCOPE_AGENT);
        int r1 = __hip_atomic_load(&ws[P_OFF + 2 * NBLK + q], __ATOMIC_RELAXED, __HIP_MEMORY_SCOPE_AGENT);
        int c0 = __hip_atomic_load(&ws[P_OFF + 3 * NBLK + q], __ATOMIC_RELAXED, __HIP_MEMORY_SCOPE_AGENT);
        int c1 = __hip_atomic_load(&ws[P_OFF + 4 * NBLK + q], __ATOMIC_RELAXED, __HIP_MEMORY_SCOPE_AGENT);
#pragma unroll
        for (int off = 16; off > 0; off >>= 1) {
            c  += __shfl_xor(c, off, 32);
            r0 = min(r0, __shfl_xor(r0, off, 32));
            r1 = max(r1, __shfl_xor(r1, off, 32));
            c0 = min(c0, __shfl_xor(c0, off, 32));
            c1 = max(c1, __shfl_xor(c1, off, 32));
        }
        if (tid == 0) {
            const int nthr = *nthr_p;
            const int dthr = *dthr_p;
            int brmn, brmx, bcmn, bcmx;
            if (c >= nthr) {
                brmn = max(r0 - dthr, 0);
                brmx = min(r1 + dthr, H - 1);
                bcmn = max(c0 - dthr, 0);
                bcmx = min(c1 + dthr, W - 1);
            } else {  // too few points -> attend everywhere
                brmn = 0; brmx = H - 1; bcmn = 0; bcmx = W - 1;
            }
            int* box = &ws[X_OFF + b * 8];
            __hip_atomic_store(&box[1], brmn, __ATOMIC_RELAXED, __HIP_MEMORY_SCOPE_AGENT);
            __hip_atomic_store(&box[2], brmx, __ATOMIC_RELAXED, __HIP_MEMORY_SCOPE_AGENT);
            __hip_atomic_store(&box[3], bcmn, __ATOMIC_RELAXED, __HIP_MEMORY_SCOPE_AGENT);
            __hip_atomic_store(&box[4], bcmx, __ATOMIC_RELAXED, __HIP_MEMORY_SCOPE_AGENT);
            __hip_atomic_store(&box[0], MAGIC, __ATOMIC_RELEASE, __HIP_MEMORY_SCOPE_AGENT);
        }
    }

    // ---------------- Phase 3: spin on batch flag, then fill own slice ---------
    if (tid == 0) {
        int* box = &ws[X_OFF + b * 8];
        while (__hip_atomic_load(&box[0], __ATOMIC_ACQUIRE, __HIP_MEMORY_SCOPE_AGENT) != MAGIC) {
            __builtin_amdgcn_s_sleep(2);
        }
        sbox[0] = __hip_atomic_load(&box[1], __ATOMIC_RELAXED, __HIP_MEMORY_SCOPE_AGENT);
        sbox[1] = __hip_atomic_load(&box[2], __ATOMIC_RELAXED, __HIP_MEMORY_SCOPE_AGENT);
        sbox[2] = __hip_atomic_load(&box[3], __ATOMIC_RELAXED, __HIP_MEMORY_SCOPE_AGENT);
        sbox[3] = __hip_atomic_load(&box[4], __ATOMIC_RELAXED, __HIP_MEMORY_SCOPE_AGENT);
    }
    __syncthreads();
    const int brmn = sbox[0], brmx = sbox[1], bcmn = sbox[2], bcmx = sbox[3];

    float4* ob = reinterpret_cast<float4*>(out) + (size_t)b * VEC;
#pragma unroll
    for (int it = 0; it < ITERS; ++it) {
        const int i4 = sbase + it * TPB;
        const int row = i4 / W4;
        const int col = (i4 - row * W4) * 4;
        const bool rin = (row >= brmn) & (row <= brmx);
        float4 v;
        v.x = (rin & (col + 0 >= bcmn) & (col + 0 <= bcmx)) ? 1.0f : 0.0f;
        v.y = (rin & (col + 1 >= bcmn) & (col + 1 <= bcmx)) ? 1.0f : 0.0f;
        v.z = (rin & (col + 2 >= bcmn) & (col + 2 <= bcmx)) ? 1.0f : 0.0f;
        v.w = (rin & (col + 3 >= bcmn) & (col + 3 <= bcmx)) ? 1.0f : 0.0f;
        ob[i4] = v;
    }
}

// ---------------------------------------------------------------------------
extern "C" void kernel_launch(void* const* d_in, const int* in_sizes, int n_in,
                              void* d_out, int out_size, void* d_ws, size_t ws_size,
                              hipStream_t stream) {
    const float* mask = (const float*)d_in[0];
    const int*   nthr = (const int*)d_in[1];
    const int*   dthr = (const int*)d_in[2];
    float*       out  = (float*)d_out;
    int*         ws   = (int*)d_ws;

    // Zero the per-batch arrival counters (ws is poisoned 0xAA each call).
    // hipMemsetAsync is graph-capture-legal (the harness itself uses it).
    hipMemsetAsync(ws, 0, B * sizeof(int), stream);

    rag_fused_kernel<<<NBLK, TPB, 0, stream>>>(mask, nthr, dthr, out, ws);
}

// Round 6
// 200.174 us; speedup vs baseline: 1.6344x; 1.6344x over previous
//
#include <hip/hip_runtime.h>

// Problem constants (reference setup_inputs: mask [64, 512, 896] f32)
#define B 64
#define H 512
#define W 896
#define W4 (W / 4)                  // 224 float4 per row
#define PIX (H * W)                 // 458752 per batch
#define VEC (PIX / 4)               // 114688 float4 per batch
#define TPB 256
#define SLICES 32                   // blocks per batch
#define VEC_SLICE (VEC / SLICES)    // 3584 float4 per block
#define ITERS (VEC_SLICE / TPB)     // 14 float4 per thread
#define NBLK (B * SLICES)           // 2048 blocks
#define PT 0.5f

typedef float f32x4 __attribute__((ext_vector_type(4)));

// ws layout: int[5][NBLK] -> cnt, rmn, rmx, cmn, cmx partials, one slot per
// reduce-block (written exactly once -> no init kernel, no atomics needed).

static __device__ __forceinline__ f32x4 nt_load4(const f32x4* p) {
    return __builtin_nontemporal_load(p);
}
static __device__ __forceinline__ void nt_store4(f32x4* p, f32x4 v) {
    __builtin_nontemporal_store(v, p);
}

// ---------------------------------------------------------------------------
// Kernel 1: per-slice count + bbox partials.
// ---------------------------------------------------------------------------
__global__ __launch_bounds__(TPB) void rag_reduce_kernel(
        const float* __restrict__ mask, int* __restrict__ ws) {
    const int bid = blockIdx.x;          // 0..NBLK-1
    const int b   = bid >> 5;            // batch (SLICES == 32)
    const int tid = threadIdx.x;
    const int sbase = (bid & (SLICES - 1)) * VEC_SLICE + tid;

    const f32x4* m = reinterpret_cast<const f32x4*>(mask) + (size_t)b * VEC;

    int cnt = 0, rmn = H, rmx = -1, cmn = W, cmx = -1;

#pragma unroll
    for (int it = 0; it < ITERS; ++it) {
        const int i4 = sbase + it * TPB;
        const f32x4 v = nt_load4(&m[i4]);
        const bool f0 = v.x > PT;
        const bool f1 = v.y > PT;
        const bool f2 = v.z > PT;
        const bool f3 = v.w > PT;
        cnt += (int)f0 + (int)f1 + (int)f2 + (int)f3;
        if (f0 | f1 | f2 | f3) {
            const int row = i4 / W4;
            const int col = (i4 - row * W4) * 4;
            rmn = min(rmn, row);
            rmx = max(rmx, row);
            const int clo = f0 ? col : (f1 ? col + 1 : (f2 ? col + 2 : col + 3));
            const int chi = f3 ? col + 3 : (f2 ? col + 2 : (f1 ? col + 1 : col));
            cmn = min(cmn, clo);
            cmx = max(cmx, chi);
        }
    }

    // Wave-64 reduce.
#pragma unroll
    for (int off = 32; off > 0; off >>= 1) {
        cnt += __shfl_down(cnt, off);
        rmn = min(rmn, __shfl_down(rmn, off));
        rmx = max(rmx, __shfl_down(rmx, off));
        cmn = min(cmn, __shfl_down(cmn, off));
        cmx = max(cmx, __shfl_down(cmx, off));
    }

    __shared__ int s[5][TPB / 64];
    const int wave = tid >> 6;
    if ((tid & 63) == 0) {
        s[0][wave] = cnt; s[1][wave] = rmn; s[2][wave] = rmx;
        s[3][wave] = cmn; s[4][wave] = cmx;
    }
    __syncthreads();
    if (tid == 0) {
#pragma unroll
        for (int wv = 1; wv < TPB / 64; ++wv) {
            cnt += s[0][wv];
            rmn = min(rmn, s[1][wv]);
            rmx = max(rmx, s[2][wv]);
            cmn = min(cmn, s[3][wv]);
            cmx = max(cmx, s[4][wv]);
        }
        ws[0 * NBLK + bid] = cnt;
        ws[1 * NBLK + bid] = rmn;
        ws[2 * NBLK + bid] = rmx;
        ws[3 * NBLK + bid] = cmn;
        ws[4 * NBLK + bid] = cmx;
    }
}

// ---------------------------------------------------------------------------
// Kernel 2: finalize box from partials (first wave) + stream output.
// ---------------------------------------------------------------------------
__global__ __launch_bounds__(TPB) void rag_fill_kernel(
        const int* __restrict__ ws,
        const int* __restrict__ nthr_p,
        const int* __restrict__ dthr_p,
        float* __restrict__ out) {
    const int bid = blockIdx.x;
    const int b   = bid >> 5;
    const int tid = threadIdx.x;

    __shared__ int sbox[4];
    if (tid < 64) {
        const int q = (b << 5) + (tid & 31);   // 32 partial slots for this batch
        int c  = ws[0 * NBLK + q];
        int r0 = ws[1 * NBLK + q];
        int r1 = ws[2 * NBLK + q];
        int c0 = ws[3 * NBLK + q];
        int c1 = ws[4 * NBLK + q];
#pragma unroll
        for (int off = 16; off > 0; off >>= 1) {
            c  += __shfl_xor(c, off, 32);
            r0 = min(r0, __shfl_xor(r0, off, 32));
            r1 = max(r1, __shfl_xor(r1, off, 32));
            c0 = min(c0, __shfl_xor(c0, off, 32));
            c1 = max(c1, __shfl_xor(c1, off, 32));
        }
        if (tid == 0) {
            const int nthr = *nthr_p;
            const int dthr = *dthr_p;
            int brmn, brmx, bcmn, bcmx;
            if (c >= nthr) {
                brmn = max(r0 - dthr, 0);
                brmx = min(r1 + dthr, H - 1);
                bcmn = max(c0 - dthr, 0);
                bcmx = min(c1 + dthr, W - 1);
            } else {  // too few points -> attend everywhere
                brmn = 0; brmx = H - 1; bcmn = 0; bcmx = W - 1;
            }
            sbox[0] = brmn; sbox[1] = brmx; sbox[2] = bcmn; sbox[3] = bcmx;
        }
    }
    __syncthreads();
    const int brmn = sbox[0];
    const unsigned rspan = (unsigned)(sbox[1] - brmn);   // brmx - brmn
    const int bcmn = sbox[2];
    const unsigned cspan = (unsigned)(sbox[3] - bcmn);   // bcmx - bcmn

    f32x4* ob = reinterpret_cast<f32x4*>(out) + (size_t)b * VEC;
    const int sbase = (bid & (SLICES - 1)) * VEC_SLICE + tid;

#pragma unroll
    for (int it = 0; it < ITERS; ++it) {
        const int i4 = sbase + it * TPB;
        const int row = i4 / W4;
        const int col = (i4 - row * W4) * 4;
        const bool rin = (unsigned)(row - brmn) <= rspan;
        f32x4 v;
        v.x = (rin & ((unsigned)(col + 0 - bcmn) <= cspan)) ? 1.0f : 0.0f;
        v.y = (rin & ((unsigned)(col + 1 - bcmn) <= cspan)) ? 1.0f : 0.0f;
        v.z = (rin & ((unsigned)(col + 2 - bcmn) <= cspan)) ? 1.0f : 0.0f;
        v.w = (rin & ((unsigned)(col + 3 - bcmn) <= cspan)) ? 1.0f : 0.0f;
        nt_store4(&ob[i4], v);
    }
}

// ---------------------------------------------------------------------------
extern "C" void kernel_launch(void* const* d_in, const int* in_sizes, int n_in,
                              void* d_out, int out_size, void* d_ws, size_t ws_size,
                              hipStream_t stream) {
    const float* mask = (const float*)d_in[0];
    const int*   nthr = (const int*)d_in[1];
    const int*   dthr = (const int*)d_in[2];
    float*       out  = (float*)d_out;
    int*         ws   = (int*)d_ws;

    rag_reduce_kernel<<<NBLK, TPB, 0, stream>>>(mask, ws);
    rag_fill_kernel<<<NBLK, TPB, 0, stream>>>(ws, nthr, dthr, out);
}